// Round 5
// baseline (548.613 us; speedup 1.0000x reference)
//
#include <hip/hip_runtime.h>
#include <hip/hip_bf16.h>

// Capsule routing: B=256, J=2, N=6912 input caps, E=16, D=8, 2 routing iters.
//   pass1: s1[b,j,e] = 0.5 * sum_n u_hat[b,j,n,e];  v1 = squash(s1)
//   pass2: l[j,n] = sum_e v1[j,e]*u_hat; c = softmax_j(l); s2 = sum_n c*u_hat
//   out = squash(s2), FP32 ([256,2,16] row-major).
//
// R5: ALL tensors are fp32. Evidence: threshold 1.664062e-02 == 0.02 * 0.8320312
// exactly (2% of ref max, NO bf16 floor => harness _any_bf16 is False); the
// "(bf16, ...)" in the assert label is a hard-coded f-string, not the dtype.
// R2-R4's bit-identical 1.21875 error == harness reading our bf16 ushort pairs
// as fp32 words (sees v[2k+1] at position k). Fix: store fp32.
#define B_ 256
#define J_ 2
#define N_ 6912
#define E_ 16
#define D_ 8
#define NT 512   // threads per block (8 waves)

__device__ __forceinline__ float bfl(unsigned u){ return __uint_as_float(u << 16); }
__device__ __forceinline__ float bfh(unsigned u){ return __uint_as_float(u & 0xffff0000u); }

// load 8 consecutive logical elements starting at element index `idx`
template<bool BF16>
__device__ __forceinline__ void load8(const void* __restrict__ base, size_t idx, float* f){
  if (BF16){
    uint4 q = *(const uint4*)((const ushort*)base + idx);
    f[0]=bfl(q.x); f[1]=bfh(q.x);
    f[2]=bfl(q.y); f[3]=bfh(q.y);
    f[4]=bfl(q.z); f[5]=bfh(q.z);
    f[6]=bfl(q.w); f[7]=bfh(q.w);
  } else {
    const float4* p = (const float4*)((const float*)base + idx);
    float4 a = p[0], c = p[1];
    f[0]=a.x; f[1]=a.y; f[2]=a.z; f[3]=a.w;
    f[4]=c.x; f[5]=c.y; f[6]=c.z; f[7]=c.w;
  }
}

// bf16 data: word bits[14:7] = low element's exponent, in [110,145] ~always
// for N(0,sigma) data. fp32 data: uniform mantissa bits there (~14% in range).
// Uniform over the tensor's first 64 words -> uniform branch, no divergence.
__device__ __forceinline__ bool looks_bf16(const unsigned* __restrict__ p){
  int cnt = 0;
  #pragma unroll
  for (int k=0;k<64;++k){
    unsigned e = (p[k] >> 7) & 0xFF;
    cnt += (e >= 110 && e <= 145) ? 1 : 0;
  }
  return cnt >= 32;
}

template<bool XB, bool WB>
__global__ __launch_bounds__(NT) void kmono(const void* __restrict__ xv,
                                            const void* __restrict__ Wv,
                                            float* __restrict__ out)
{
  if (looks_bf16((const unsigned*)xv) != XB) return;   // uniform early-exit
  if (looks_bf16((const unsigned*)Wv) != WB) return;

  const int b    = blockIdx.x;
  const int tid  = threadIdx.x;
  const int wv   = tid >> 6;
  const int lane = tid & 63;

  __shared__ float wred[8*33];   // per-wave partials, stride 33
  __shared__ float vsh[32];      // v1 broadcast

  // ---------------- pass 1: s1 = sum_n u_hat ----------------
  float acc[32];
  #pragma unroll
  for (int i=0;i<32;++i) acc[i]=0.f;

  for (int n = tid; n < N_; n += NT){
    float xf[8]; load8<XB>(xv, ((size_t)b*N_ + n)*D_, xf);
    #pragma unroll
    for (int j=0;j<J_;++j){
      const size_t wb = ((size_t)j*N_ + n)*(E_*D_);
      #pragma unroll
      for (int e=0;e<E_;++e){
        float wf[8]; load8<WB>(Wv, wb + e*D_, wf);
        float a = acc[j*16+e];
        #pragma unroll
        for (int d=0;d<8;++d) a = fmaf(wf[d], xf[d], a);
        acc[j*16+e] = a;
      }
    }
  }
  // wave butterfly reduce each of the 32 accumulators
  #pragma unroll
  for (int i=0;i<32;++i){
    float v = acc[i];
    #pragma unroll
    for (int off=32; off; off>>=1) v += __shfl_xor(v, off);
    acc[i] = v;
  }
  if (lane == 0){
    #pragma unroll
    for (int i=0;i<32;++i) wred[wv*33 + i] = acc[i];
  }
  __syncthreads();
  if (tid < 32){
    float s = 0.f;
    #pragma unroll
    for (int w=0;w<8;++w) s += wred[w*33 + tid];
    wred[tid] = 0.5f * s;          // c = 0.5 in routing iter 1; stash in row 0
  }                                 // (thread t only touches column t: safe)
  __syncthreads();
  if (tid < 32){
    const int j = tid >> 4;
    float n2 = 0.f;
    #pragma unroll
    for (int e=0;e<16;++e){ const float sv = wred[j*16+e]; n2 = fmaf(sv,sv,n2); }
    const float f = (n2/(1.f+n2)) * rsqrtf(n2 + 1e-9f);
    vsh[tid] = wred[tid] * f;      // v1[b, j, e]
  }
  __syncthreads();
  float vv[32];
  #pragma unroll
  for (int i=0;i<32;++i) vv[i] = vsh[i];

  // ---------------- pass 2: routed sum ----------------
  #pragma unroll
  for (int i=0;i<32;++i) acc[i]=0.f;

  for (int n = tid; n < N_; n += NT){
    float xf[8]; load8<XB>(xv, ((size_t)b*N_ + n)*D_, xf);
    float u[32];
    #pragma unroll
    for (int j=0;j<J_;++j){
      const size_t wb = ((size_t)j*N_ + n)*(E_*D_);
      #pragma unroll
      for (int e=0;e<E_;++e){
        float wf[8]; load8<WB>(Wv, wb + e*D_, wf);
        float a = 0.f;
        #pragma unroll
        for (int d=0;d<8;++d) a = fmaf(wf[d], xf[d], a);
        u[j*16+e] = a;
      }
    }
    float bl0=0.f, bl1=0.f;
    #pragma unroll
    for (int e=0;e<16;++e){
      bl0 = fmaf(vv[e],    u[e],    bl0);
      bl1 = fmaf(vv[16+e], u[16+e], bl1);
    }
    const float c0 = 1.f/(1.f + __expf(bl1 - bl0));  // softmax over the 2 caps
    const float c1 = 1.f - c0;
    #pragma unroll
    for (int e=0;e<16;++e){
      acc[e]    = fmaf(c0, u[e],    acc[e]);
      acc[16+e] = fmaf(c1, u[16+e], acc[16+e]);
    }
  }
  #pragma unroll
  for (int i=0;i<32;++i){
    float v = acc[i];
    #pragma unroll
    for (int off=32; off; off>>=1) v += __shfl_xor(v, off);
    acc[i] = v;
  }
  __syncthreads();   // wred reuse
  if (lane == 0){
    #pragma unroll
    for (int i=0;i<32;++i) wred[wv*33 + i] = acc[i];
  }
  __syncthreads();
  if (tid < 32){
    float s = 0.f;
    #pragma unroll
    for (int w=0;w<8;++w) s += wred[w*33 + tid];
    wred[tid] = s;                 // s2 (no 0.5 here)
  }
  __syncthreads();
  if (tid < 32){
    const int j = tid >> 4;
    float n2 = 0.f;
    #pragma unroll
    for (int e=0;e<16;++e){ const float sv = wred[j*16+e]; n2 = fmaf(sv,sv,n2); }
    const float f = (n2/(1.f+n2)) * rsqrtf(n2 + 1e-9f);
    out[(size_t)b*32 + tid] = wred[tid] * f;    // FP32 store
  }
}

extern "C" void kernel_launch(void* const* d_in, const int* in_sizes, int n_in,
                              void* d_out, int out_size, void* d_ws, size_t ws_size,
                              hipStream_t stream)
{
  // x: [256,6912,8] (14,155,776 elems), W: [2,6912,16,8] (1,769,472 elems).
  const void* x = d_in[0];
  const void* W = d_in[1];
  if (n_in >= 2 && in_sizes[0] < in_sizes[1]){ x = d_in[1]; W = d_in[0]; }

  float* out = (float*)d_out;     // FP32 [256,2,16]
  (void)d_ws; (void)ws_size;

  // All 4 dtype combos; exactly one runs, the rest exit uniformly in ~us.
  kmono<false,false><<<B_, NT, 0, stream>>>(x, W, out);
  kmono<false,true ><<<B_, NT, 0, stream>>>(x, W, out);
  kmono<true ,false><<<B_, NT, 0, stream>>>(x, W, out);
  kmono<true ,true ><<<B_, NT, 0, stream>>>(x, W, out);
}

// Round 7
// 256.350 us; speedup vs baseline: 2.1401x; 2.1401x over previous
//
#include <hip/hip_runtime.h>

// Capsule routing: B=256, J=2, N=6912, E=16, D=8, 2 routing iters. All fp32
// (proven R5: FETCH 110.7MB = 2 x 56.6MB fp32-x; absmax 9.8e-4).
//   pass1: s1[b,j,e] = sum_n u_hat;  v1 = squash(0.5*s1)
//   pass2: l[j,n] = sum_e v1*u_hat; c = sigmoid(l0-l1); s2 = sum_n c*u_hat
//   out = squash(s2) fp32 [256,2,16].
// R7 = R6 with the `#pragma on same line as code` compile error fixed.
// R5 was latency-bound (VALUBusy 7%, HBM 2.8%): lane=n made every W load
// shatter into 64 cache lines/wave. Switch to lane=b: W loads wave-uniform
// (1 line, HW broadcast), x streamed per-lane. Global sync between passes via
// d_ws (5-kernel chain); R5 monolith kept as fallback if ws_size < 96KB.
#define B_ 256
#define J_ 2
#define N_ 6912
#define E_ 16
#define D_ 8
#define NPW 9     // n per wave; 768 chunks; grid (192,4)
#define CGX 192   // gridDim.x for pass kernels

__global__ void kzero(float* __restrict__ ws){
  const int t = blockIdx.x*256 + threadIdx.x;   // grid 32 -> 8192 threads
  ws[t] = 0.f;           // s1
  ws[16384 + t] = 0.f;   // s2
}

// Block-level reduction of per-thread acc[32] (same b per lane across the 4
// waves) -> atomicAdd into dst[b*32 + i]. Stride-33 rows: conflict-free.
__device__ __forceinline__ void reduce_and_add(const float* __restrict__ acc,
                                               float* __restrict__ dst_base,
                                               int btile)
{
  __shared__ float red[256*33];
  const int tid = threadIdx.x;
  #pragma unroll
  for (int i=0;i<32;++i) red[tid*33 + i] = acc[i];
  __syncthreads();
  const int bl = tid >> 2;          // local b
  const int i0 = (tid & 3) * 8;     // 8-elem segment
  float* dst = dst_base + ((size_t)btile*64 + bl)*32 + i0;
  #pragma unroll
  for (int k=0;k<8;++k){
    float v = 0.f;
    #pragma unroll
    for (int w=0; w<4; ++w) v += red[(w*64 + bl)*33 + i0 + k];
    atomicAdd(dst + k, v);
  }
}

// grid (CGX, 4): blockIdx.y = btile (64 b), 4 waves = 4 n-chunks of NPW.
__global__ __launch_bounds__(256) void kpass1(const float* __restrict__ x,
                                              const float* __restrict__ W,
                                              float* __restrict__ s1)
{
  const int tid  = threadIdx.x;
  const int lane = tid & 63;
  const int wv   = __builtin_amdgcn_readfirstlane(tid >> 6);
  const int b    = blockIdx.y*64 + lane;
  const int n0   = (blockIdx.x*4 + wv) * NPW;

  float acc[32];
  #pragma unroll
  for (int i=0;i<32;++i) acc[i]=0.f;

  const float* xp = x + ((size_t)b*N_ + n0)*D_;

  #pragma unroll 1
  for (int ni=0; ni<NPW; ++ni){
    const float4 xa = *(const float4*)(xp + ni*8);
    const float4 xb = *(const float4*)(xp + ni*8 + 4);
    const int n = n0 + ni;
    #pragma unroll
    for (int j=0;j<J_;++j){
      const float* wp = W + ((size_t)j*N_ + n)*(E_*D_);   // wave-uniform
      #pragma unroll
      for (int e=0;e<E_;++e){
        const float4 wa = *(const float4*)(wp + e*8);
        const float4 wb = *(const float4*)(wp + e*8 + 4);
        float a = acc[j*16+e];
        a = fmaf(wa.x, xa.x, a); a = fmaf(wa.y, xa.y, a);
        a = fmaf(wa.z, xa.z, a); a = fmaf(wa.w, xa.w, a);
        a = fmaf(wb.x, xb.x, a); a = fmaf(wb.y, xb.y, a);
        a = fmaf(wb.z, xb.z, a); a = fmaf(wb.w, xb.w, a);
        acc[j*16+e] = a;
      }
    }
  }
  reduce_and_add(acc, s1, blockIdx.y);
}

// v1 = squash(0.5 * s1); one thread per (b,j).
__global__ void ksquash_mid(const float* __restrict__ s1, float* __restrict__ v1){
  const int t = blockIdx.x*256 + threadIdx.x;
  if (t >= B_*J_) return;
  float s[16]; float n2 = 0.f;
  #pragma unroll
  for (int e=0;e<16;++e){ const float sv = 0.5f*s1[t*16+e]; s[e]=sv; n2 = fmaf(sv,sv,n2); }
  const float f = (n2/(1.f+n2)) * rsqrtf(n2 + 1e-9f);
  #pragma unroll
  for (int e=0;e<16;++e) v1[t*16+e] = s[e]*f;
}

__global__ __launch_bounds__(256) void kpass2(const float* __restrict__ x,
                                              const float* __restrict__ W,
                                              const float* __restrict__ v1,
                                              float* __restrict__ s2)
{
  const int tid  = threadIdx.x;
  const int lane = tid & 63;
  const int wv   = __builtin_amdgcn_readfirstlane(tid >> 6);
  const int b    = blockIdx.y*64 + lane;
  const int n0   = (blockIdx.x*4 + wv) * NPW;

  float vv[32];
  {
    const float4* vp = (const float4*)(v1 + (size_t)b*32);
    #pragma unroll
    for (int q=0;q<8;++q){
      const float4 t4 = vp[q];
      vv[q*4+0]=t4.x; vv[q*4+1]=t4.y; vv[q*4+2]=t4.z; vv[q*4+3]=t4.w;
    }
  }

  float acc[32];
  #pragma unroll
  for (int i=0;i<32;++i) acc[i]=0.f;

  const float* xp = x + ((size_t)b*N_ + n0)*D_;

  #pragma unroll 1
  for (int ni=0; ni<NPW; ++ni){
    const float4 xa = *(const float4*)(xp + ni*8);
    const float4 xb = *(const float4*)(xp + ni*8 + 4);
    const int n = n0 + ni;
    float u[32];
    #pragma unroll
    for (int j=0;j<J_;++j){
      const float* wp = W + ((size_t)j*N_ + n)*(E_*D_);   // wave-uniform
      #pragma unroll
      for (int e=0;e<E_;++e){
        const float4 wa = *(const float4*)(wp + e*8);
        const float4 wb = *(const float4*)(wp + e*8 + 4);
        float a;
        a = wa.x*xa.x;           a = fmaf(wa.y, xa.y, a);
        a = fmaf(wa.z, xa.z, a); a = fmaf(wa.w, xa.w, a);
        a = fmaf(wb.x, xb.x, a); a = fmaf(wb.y, xb.y, a);
        a = fmaf(wb.z, xb.z, a); a = fmaf(wb.w, xb.w, a);
        u[j*16+e] = a;
      }
    }
    float l0=0.f, l1=0.f;
    #pragma unroll
    for (int e=0;e<16;++e){
      l0 = fmaf(vv[e],    u[e],    l0);
      l1 = fmaf(vv[16+e], u[16+e], l1);
    }
    const float c0 = 1.f/(1.f + __expf(l1 - l0));   // softmax over 2 caps
    const float c1 = 1.f - c0;
    #pragma unroll
    for (int e=0;e<16;++e){
      acc[e]    = fmaf(c0, u[e],    acc[e]);
      acc[16+e] = fmaf(c1, u[16+e], acc[16+e]);
    }
  }
  reduce_and_add(acc, s2, blockIdx.y);
}

// out = squash(s2), fp32.
__global__ void ksquash_out(const float* __restrict__ s2, float* __restrict__ out){
  const int t = blockIdx.x*256 + threadIdx.x;
  if (t >= B_*J_) return;
  float s[16]; float n2 = 0.f;
  #pragma unroll
  for (int e=0;e<16;++e){ const float sv = s2[t*16+e]; s[e]=sv; n2 = fmaf(sv,sv,n2); }
  const float f = (n2/(1.f+n2)) * rsqrtf(n2 + 1e-9f);
  #pragma unroll
  for (int e=0;e<16;++e) out[t*16+e] = s[e]*f;
}

// ---------- fallback: R5's proven monolithic kernel (fp32-only) ----------
#define NT 512
__global__ __launch_bounds__(NT) void kmono(const float* __restrict__ x,
                                            const float* __restrict__ W,
                                            float* __restrict__ out)
{
  const int b    = blockIdx.x;
  const int tid  = threadIdx.x;
  const int wv   = tid >> 6;
  const int lane = tid & 63;
  __shared__ float wred[8*33];
  __shared__ float vsh[32];

  float acc[32];
  #pragma unroll
  for (int i=0;i<32;++i) acc[i]=0.f;
  for (int n = tid; n < N_; n += NT){
    const float4 xa = *(const float4*)(x + ((size_t)b*N_ + n)*D_);
    const float4 xb = *(const float4*)(x + ((size_t)b*N_ + n)*D_ + 4);
    #pragma unroll
    for (int j=0;j<J_;++j){
      const float* wp = W + ((size_t)j*N_ + n)*(E_*D_);
      #pragma unroll
      for (int e=0;e<E_;++e){
        const float4 wa = *(const float4*)(wp + e*8);
        const float4 wb = *(const float4*)(wp + e*8 + 4);
        float a = acc[j*16+e];
        a = fmaf(wa.x,xa.x,a); a = fmaf(wa.y,xa.y,a); a = fmaf(wa.z,xa.z,a); a = fmaf(wa.w,xa.w,a);
        a = fmaf(wb.x,xb.x,a); a = fmaf(wb.y,xb.y,a); a = fmaf(wb.z,xb.z,a); a = fmaf(wb.w,xb.w,a);
        acc[j*16+e] = a;
      }
    }
  }
  #pragma unroll
  for (int i=0;i<32;++i){
    float v = acc[i];
    #pragma unroll
    for (int off=32; off; off>>=1) v += __shfl_xor(v, off);
    acc[i] = v;
  }
  if (lane == 0){
    #pragma unroll
    for (int i=0;i<32;++i) wred[wv*33 + i] = acc[i];
  }
  __syncthreads();
  if (tid < 32){
    float s = 0.f;
    #pragma unroll
    for (int w=0;w<8;++w) s += wred[w*33 + tid];
    wred[tid] = 0.5f * s;
  }
  __syncthreads();
  if (tid < 32){
    const int j = tid >> 4; float n2 = 0.f;
    #pragma unroll
    for (int e=0;e<16;++e){ const float sv = wred[j*16+e]; n2 = fmaf(sv,sv,n2); }
    vsh[tid] = wred[tid] * (n2/(1.f+n2)) * rsqrtf(n2 + 1e-9f);
  }
  __syncthreads();
  float vv[32];
  #pragma unroll
  for (int i=0;i<32;++i) vv[i] = vsh[i];

  #pragma unroll
  for (int i=0;i<32;++i) acc[i]=0.f;
  for (int n = tid; n < N_; n += NT){
    const float4 xa = *(const float4*)(x + ((size_t)b*N_ + n)*D_);
    const float4 xb = *(const float4*)(x + ((size_t)b*N_ + n)*D_ + 4);
    float u[32];
    #pragma unroll
    for (int j=0;j<J_;++j){
      const float* wp = W + ((size_t)j*N_ + n)*(E_*D_);
      #pragma unroll
      for (int e=0;e<E_;++e){
        const float4 wa = *(const float4*)(wp + e*8);
        const float4 wb = *(const float4*)(wp + e*8 + 4);
        float a;
        a = wa.x*xa.x; a = fmaf(wa.y,xa.y,a); a = fmaf(wa.z,xa.z,a); a = fmaf(wa.w,xa.w,a);
        a = fmaf(wb.x,xb.x,a); a = fmaf(wb.y,xb.y,a); a = fmaf(wb.z,xb.z,a); a = fmaf(wb.w,xb.w,a);
        u[j*16+e] = a;
      }
    }
    float l0=0.f, l1=0.f;
    #pragma unroll
    for (int e=0;e<16;++e){ l0 = fmaf(vv[e],u[e],l0); l1 = fmaf(vv[16+e],u[16+e],l1); }
    const float c0 = 1.f/(1.f + __expf(l1 - l0));
    const float c1 = 1.f - c0;
    #pragma unroll
    for (int e=0;e<16;++e){ acc[e] = fmaf(c0,u[e],acc[e]); acc[16+e] = fmaf(c1,u[16+e],acc[16+e]); }
  }
  #pragma unroll
  for (int i=0;i<32;++i){
    float v = acc[i];
    #pragma unroll
    for (int off=32; off; off>>=1) v += __shfl_xor(v, off);
    acc[i] = v;
  }
  __syncthreads();
  if (lane == 0){
    #pragma unroll
    for (int i=0;i<32;++i) wred[wv*33 + i] = acc[i];
  }
  __syncthreads();
  if (tid < 32){
    float s = 0.f;
    #pragma unroll
    for (int w=0;w<8;++w) s += wred[w*33 + tid];
    wred[tid] = s;
  }
  __syncthreads();
  if (tid < 32){
    const int j = tid >> 4; float n2 = 0.f;
    #pragma unroll
    for (int e=0;e<16;++e){ const float sv = wred[j*16+e]; n2 = fmaf(sv,sv,n2); }
    out[(size_t)b*32 + tid] = wred[tid] * (n2/(1.f+n2)) * rsqrtf(n2 + 1e-9f);
  }
}

extern "C" void kernel_launch(void* const* d_in, const int* in_sizes, int n_in,
                              void* d_out, int out_size, void* d_ws, size_t ws_size,
                              hipStream_t stream)
{
  const float* x = (const float*)d_in[0];   // [256,6912,8]
  const float* W = (const float*)d_in[1];   // [2,6912,16,8]
  if (n_in >= 2 && in_sizes[0] < in_sizes[1]){
    x = (const float*)d_in[1]; W = (const float*)d_in[0];
  }
  float* out = (float*)d_out;               // fp32 [256,2,16]

  if (ws_size >= 3*8192*sizeof(float)){
    float* wsf = (float*)d_ws;
    float* s1 = wsf;            // 8192
    float* v1 = wsf + 8192;     // 8192
    float* s2 = wsf + 16384;    // 8192
    kzero<<<32, 256, 0, stream>>>(wsf);
    kpass1<<<dim3(CGX,4), 256, 0, stream>>>(x, W, s1);
    ksquash_mid<<<2, 256, 0, stream>>>(s1, v1);
    kpass2<<<dim3(CGX,4), 256, 0, stream>>>(x, W, v1, s2);
    ksquash_out<<<2, 256, 0, stream>>>(s2, out);
  } else {
    kmono<<<B_, NT, 0, stream>>>(x, W, out);   // proven fallback (549 us)
  }
}

// Round 8
// 187.908 us; speedup vs baseline: 2.9196x; 1.3642x over previous
//
#include <hip/hip_runtime.h>

// Capsule routing: B=256, J=2, N=6912, E=16, D=8, 2 routing iters. All fp32.
//   pass1: s1[b,j,e] = sum_n u_hat;  v1 = squash(0.5*s1)
//   pass2: l[j,n] = sum_e v1*u_hat; c = sigmoid(l0-l1); s2 = sum_n c*u_hat
//   out = squash(s2) fp32 [256,2,16].
// R8: R7 ran 103us/pass with VALUBusy 9%, WRITE_SIZE 48MB (= 1.57M global
// atomicAdds write-through past L2) and VGPR=64 (loads issued in ~10
// serialized batches per n). Fix: (a) non-atomic per-block partials + fused
// reduce/squash kernel; (b) __launch_bounds__(256,3) -> ~170 VGPR cap for
// deep load batching. Fallbacks: R7 atomic path (96KB ws), R5 monolith.
#define B_ 256
#define J_ 2
#define N_ 6912
#define E_ 16
#define D_ 8
#define NPW 9     // n per wave
#define CGX 192   // n-chunk groups; grid (CGX,4); 768 blocks; blockLinear = cx*4+btile

// ---------------- main path: partials, no atomics ----------------

// Block-level reduction of per-thread acc[32] -> non-atomic store of the
// block's 2048-float partial (coalesced). red stride 33: conflict-free.
__device__ __forceinline__ void reduce_and_store(const float* __restrict__ acc,
                                                 float* __restrict__ blk_dst)
{
  __shared__ float red[256*33];
  const int tid = threadIdx.x;
  #pragma unroll
  for (int i=0;i<32;++i) red[tid*33 + i] = acc[i];
  __syncthreads();
  const int bl = tid >> 2;          // local b
  const int i0 = (tid & 3) * 8;     // 8-elem segment
  float v[8];
  #pragma unroll
  for (int k=0;k<8;++k){
    float s = 0.f;
    #pragma unroll
    for (int w=0; w<4; ++w) s += red[(w*64 + bl)*33 + i0 + k];
    v[k] = s;
  }
  float* dst = blk_dst + bl*32 + i0;   // thread-consecutive: coalesced
  *(float4*)(dst)     = make_float4(v[0],v[1],v[2],v[3]);
  *(float4*)(dst + 4) = make_float4(v[4],v[5],v[6],v[7]);
}

// grid (CGX, 4): blockIdx.y = btile (64 b), 4 waves = 4 n-chunks of NPW.
__global__ __launch_bounds__(256, 3) void kpass1(const float* __restrict__ x,
                                                 const float* __restrict__ W,
                                                 float* __restrict__ partial)
{
  const int tid  = threadIdx.x;
  const int lane = tid & 63;
  const int wv   = __builtin_amdgcn_readfirstlane(tid >> 6);
  const int b    = blockIdx.y*64 + lane;
  const int n0   = (blockIdx.x*4 + wv) * NPW;

  float acc[32];
  #pragma unroll
  for (int i=0;i<32;++i) acc[i]=0.f;

  const float* xp = x + ((size_t)b*N_ + n0)*D_;

  #pragma unroll 3
  for (int ni=0; ni<NPW; ++ni){
    const float4 xa = *(const float4*)(xp + ni*8);
    const float4 xb = *(const float4*)(xp + ni*8 + 4);
    const int n = n0 + ni;
    #pragma unroll
    for (int j=0;j<J_;++j){
      const float* wp = W + ((size_t)j*N_ + n)*(E_*D_);   // wave-uniform
      #pragma unroll
      for (int e=0;e<E_;++e){
        const float4 wa = *(const float4*)(wp + e*8);
        const float4 wb = *(const float4*)(wp + e*8 + 4);
        float a = acc[j*16+e];
        a = fmaf(wa.x, xa.x, a); a = fmaf(wa.y, xa.y, a);
        a = fmaf(wa.z, xa.z, a); a = fmaf(wa.w, xa.w, a);
        a = fmaf(wb.x, xb.x, a); a = fmaf(wb.y, xb.y, a);
        a = fmaf(wb.z, xb.z, a); a = fmaf(wb.w, xb.w, a);
        acc[j*16+e] = a;
      }
    }
  }
  reduce_and_store(acc, partial + (size_t)(blockIdx.x*4 + blockIdx.y)*2048);
}

__global__ __launch_bounds__(256, 3) void kpass2(const float* __restrict__ x,
                                                 const float* __restrict__ W,
                                                 const float* __restrict__ v1,
                                                 float* __restrict__ partial)
{
  const int tid  = threadIdx.x;
  const int lane = tid & 63;
  const int wv   = __builtin_amdgcn_readfirstlane(tid >> 6);
  const int b    = blockIdx.y*64 + lane;
  const int n0   = (blockIdx.x*4 + wv) * NPW;

  float vv[32];
  {
    const float4* vp = (const float4*)(v1 + (size_t)b*32);
    #pragma unroll
    for (int q=0;q<8;++q){
      const float4 t4 = vp[q];
      vv[q*4+0]=t4.x; vv[q*4+1]=t4.y; vv[q*4+2]=t4.z; vv[q*4+3]=t4.w;
    }
  }

  float acc[32];
  #pragma unroll
  for (int i=0;i<32;++i) acc[i]=0.f;

  const float* xp = x + ((size_t)b*N_ + n0)*D_;

  #pragma unroll 3
  for (int ni=0; ni<NPW; ++ni){
    const float4 xa = *(const float4*)(xp + ni*8);
    const float4 xb = *(const float4*)(xp + ni*8 + 4);
    const int n = n0 + ni;
    float u[32];
    #pragma unroll
    for (int j=0;j<J_;++j){
      const float* wp = W + ((size_t)j*N_ + n)*(E_*D_);   // wave-uniform
      #pragma unroll
      for (int e=0;e<E_;++e){
        const float4 wa = *(const float4*)(wp + e*8);
        const float4 wb = *(const float4*)(wp + e*8 + 4);
        float a;
        a = wa.x*xa.x;           a = fmaf(wa.y, xa.y, a);
        a = fmaf(wa.z, xa.z, a); a = fmaf(wa.w, xa.w, a);
        a = fmaf(wb.x, xb.x, a); a = fmaf(wb.y, xb.y, a);
        a = fmaf(wb.z, xb.z, a); a = fmaf(wb.w, xb.w, a);
        u[j*16+e] = a;
      }
    }
    float l0=0.f, l1=0.f;
    #pragma unroll
    for (int e=0;e<16;++e){
      l0 = fmaf(vv[e],    u[e],    l0);
      l1 = fmaf(vv[16+e], u[16+e], l1);
    }
    const float c0 = 1.f/(1.f + __expf(l1 - l0));   // softmax over 2 caps
    const float c1 = 1.f - c0;
    #pragma unroll
    for (int e=0;e<16;++e){
      acc[e]    = fmaf(c0, u[e],    acc[e]);
      acc[16+e] = fmaf(c1, u[16+e], acc[16+e]);
    }
  }
  reduce_and_store(acc, partial + (size_t)(blockIdx.x*4 + blockIdx.y)*2048);
}

// Fused reduce (sum 192 chunk-partials per output) + squash. t = b*32+j*16+e;
// 16-lane shfl butterfly computes |s|^2 within each (b,j) group.
// SCALE: 0.5 for routing iter 1 (kred1 -> v1), 1.0 for iter 2 (kred2 -> out).
template<bool HALF>
__global__ __launch_bounds__(256) void kred(const float* __restrict__ partial,
                                            float* __restrict__ dst)
{
  const int t = blockIdx.x*256 + threadIdx.x;     // grid 32 -> 8192
  const int btile = t >> 11, q = t & 2047;
  const float* p = partial + (size_t)btile*2048 + q;
  float s = 0.f;
  #pragma unroll 8
  for (int cx=0; cx<CGX; ++cx) s += p[(size_t)cx*8192];
  if (HALF) s *= 0.5f;
  float n2 = s*s;
  #pragma unroll
  for (int m=1; m<16; m<<=1) n2 += __shfl_xor(n2, m);
  const float f = (n2/(1.f+n2)) * rsqrtf(n2 + 1e-9f);
  dst[t] = s * f;
}

// ---------------- fallback A: R7 atomic path (96 KB ws) ----------------

__global__ void kzero(float* __restrict__ ws){
  const int t = blockIdx.x*256 + threadIdx.x;
  ws[t] = 0.f;           // s1
  ws[16384 + t] = 0.f;   // s2
}

__device__ __forceinline__ void reduce_and_add(const float* __restrict__ acc,
                                               float* __restrict__ dst_base,
                                               int btile)
{
  __shared__ float red[256*33];
  const int tid = threadIdx.x;
  #pragma unroll
  for (int i=0;i<32;++i) red[tid*33 + i] = acc[i];
  __syncthreads();
  const int bl = tid >> 2;
  const int i0 = (tid & 3) * 8;
  float* dst = dst_base + ((size_t)btile*64 + bl)*32 + i0;
  #pragma unroll
  for (int k=0;k<8;++k){
    float v = 0.f;
    #pragma unroll
    for (int w=0; w<4; ++w) v += red[(w*64 + bl)*33 + i0 + k];
    atomicAdd(dst + k, v);
  }
}

__global__ __launch_bounds__(256) void kpass1a(const float* __restrict__ x,
                                               const float* __restrict__ W,
                                               float* __restrict__ s1)
{
  const int tid  = threadIdx.x;
  const int lane = tid & 63;
  const int wv   = __builtin_amdgcn_readfirstlane(tid >> 6);
  const int b    = blockIdx.y*64 + lane;
  const int n0   = (blockIdx.x*4 + wv) * NPW;
  float acc[32];
  #pragma unroll
  for (int i=0;i<32;++i) acc[i]=0.f;
  const float* xp = x + ((size_t)b*N_ + n0)*D_;
  #pragma unroll 1
  for (int ni=0; ni<NPW; ++ni){
    const float4 xa = *(const float4*)(xp + ni*8);
    const float4 xb = *(const float4*)(xp + ni*8 + 4);
    const int n = n0 + ni;
    #pragma unroll
    for (int j=0;j<J_;++j){
      const float* wp = W + ((size_t)j*N_ + n)*(E_*D_);
      #pragma unroll
      for (int e=0;e<E_;++e){
        const float4 wa = *(const float4*)(wp + e*8);
        const float4 wb = *(const float4*)(wp + e*8 + 4);
        float a = acc[j*16+e];
        a = fmaf(wa.x,xa.x,a); a = fmaf(wa.y,xa.y,a); a = fmaf(wa.z,xa.z,a); a = fmaf(wa.w,xa.w,a);
        a = fmaf(wb.x,xb.x,a); a = fmaf(wb.y,xb.y,a); a = fmaf(wb.z,xb.z,a); a = fmaf(wb.w,xb.w,a);
        acc[j*16+e] = a;
      }
    }
  }
  reduce_and_add(acc, s1, blockIdx.y);
}

__global__ void ksquash_mid(const float* __restrict__ s1, float* __restrict__ v1){
  const int t = blockIdx.x*256 + threadIdx.x;
  if (t >= B_*J_) return;
  float s[16]; float n2 = 0.f;
  #pragma unroll
  for (int e=0;e<16;++e){ const float sv = 0.5f*s1[t*16+e]; s[e]=sv; n2 = fmaf(sv,sv,n2); }
  const float f = (n2/(1.f+n2)) * rsqrtf(n2 + 1e-9f);
  #pragma unroll
  for (int e=0;e<16;++e) v1[t*16+e] = s[e]*f;
}

__global__ __launch_bounds__(256) void kpass2a(const float* __restrict__ x,
                                               const float* __restrict__ W,
                                               const float* __restrict__ v1,
                                               float* __restrict__ s2)
{
  const int tid  = threadIdx.x;
  const int lane = tid & 63;
  const int wv   = __builtin_amdgcn_readfirstlane(tid >> 6);
  const int b    = blockIdx.y*64 + lane;
  const int n0   = (blockIdx.x*4 + wv) * NPW;
  float vv[32];
  {
    const float4* vp = (const float4*)(v1 + (size_t)b*32);
    #pragma unroll
    for (int q=0;q<8;++q){
      const float4 t4 = vp[q];
      vv[q*4+0]=t4.x; vv[q*4+1]=t4.y; vv[q*4+2]=t4.z; vv[q*4+3]=t4.w;
    }
  }
  float acc[32];
  #pragma unroll
  for (int i=0;i<32;++i) acc[i]=0.f;
  const float* xp = x + ((size_t)b*N_ + n0)*D_;
  #pragma unroll 1
  for (int ni=0; ni<NPW; ++ni){
    const float4 xa = *(const float4*)(xp + ni*8);
    const float4 xb = *(const float4*)(xp + ni*8 + 4);
    const int n = n0 + ni;
    float u[32];
    #pragma unroll
    for (int j=0;j<J_;++j){
      const float* wp = W + ((size_t)j*N_ + n)*(E_*D_);
      #pragma unroll
      for (int e=0;e<E_;++e){
        const float4 wa = *(const float4*)(wp + e*8);
        const float4 wb = *(const float4*)(wp + e*8 + 4);
        float a;
        a = wa.x*xa.x; a = fmaf(wa.y,xa.y,a); a = fmaf(wa.z,xa.z,a); a = fmaf(wa.w,xa.w,a);
        a = fmaf(wb.x,xb.x,a); a = fmaf(wb.y,xb.y,a); a = fmaf(wb.z,xb.z,a); a = fmaf(wb.w,xb.w,a);
        u[j*16+e] = a;
      }
    }
    float l0=0.f, l1=0.f;
    #pragma unroll
    for (int e=0;e<16;++e){ l0 = fmaf(vv[e],u[e],l0); l1 = fmaf(vv[16+e],u[16+e],l1); }
    const float c0 = 1.f/(1.f + __expf(l1 - l0));
    const float c1 = 1.f - c0;
    #pragma unroll
    for (int e=0;e<16;++e){ acc[e] = fmaf(c0,u[e],acc[e]); acc[16+e] = fmaf(c1,u[16+e],acc[16+e]); }
  }
  reduce_and_add(acc, s2, blockIdx.y);
}

__global__ void ksquash_out(const float* __restrict__ s2, float* __restrict__ out){
  const int t = blockIdx.x*256 + threadIdx.x;
  if (t >= B_*J_) return;
  float s[16]; float n2 = 0.f;
  #pragma unroll
  for (int e=0;e<16;++e){ const float sv = s2[t*16+e]; s[e]=sv; n2 = fmaf(sv,sv,n2); }
  const float f = (n2/(1.f+n2)) * rsqrtf(n2 + 1e-9f);
  #pragma unroll
  for (int e=0;e<16;++e) out[t*16+e] = s[e]*f;
}

// ---------------- fallback B: R5 monolithic (no ws) ----------------
#define NT 512
__global__ __launch_bounds__(NT) void kmono(const float* __restrict__ x,
                                            const float* __restrict__ W,
                                            float* __restrict__ out)
{
  const int b    = blockIdx.x;
  const int tid  = threadIdx.x;
  const int wv   = tid >> 6;
  const int lane = tid & 63;
  __shared__ float wred[8*33];
  __shared__ float vsh[32];

  float acc[32];
  #pragma unroll
  for (int i=0;i<32;++i) acc[i]=0.f;
  for (int n = tid; n < N_; n += NT){
    const float4 xa = *(const float4*)(x + ((size_t)b*N_ + n)*D_);
    const float4 xb = *(const float4*)(x + ((size_t)b*N_ + n)*D_ + 4);
    #pragma unroll
    for (int j=0;j<J_;++j){
      const float* wp = W + ((size_t)j*N_ + n)*(E_*D_);
      #pragma unroll
      for (int e=0;e<E_;++e){
        const float4 wa = *(const float4*)(wp + e*8);
        const float4 wb = *(const float4*)(wp + e*8 + 4);
        float a = acc[j*16+e];
        a = fmaf(wa.x,xa.x,a); a = fmaf(wa.y,xa.y,a); a = fmaf(wa.z,xa.z,a); a = fmaf(wa.w,xa.w,a);
        a = fmaf(wb.x,xb.x,a); a = fmaf(wb.y,xb.y,a); a = fmaf(wb.z,xb.z,a); a = fmaf(wb.w,xb.w,a);
        acc[j*16+e] = a;
      }
    }
  }
  #pragma unroll
  for (int i=0;i<32;++i){
    float v = acc[i];
    #pragma unroll
    for (int off=32; off; off>>=1) v += __shfl_xor(v, off);
    acc[i] = v;
  }
  if (lane == 0){
    #pragma unroll
    for (int i=0;i<32;++i) wred[wv*33 + i] = acc[i];
  }
  __syncthreads();
  if (tid < 32){
    float s = 0.f;
    #pragma unroll
    for (int w=0;w<8;++w) s += wred[w*33 + tid];
    wred[tid] = 0.5f * s;
  }
  __syncthreads();
  if (tid < 32){
    const int j = tid >> 4; float n2 = 0.f;
    #pragma unroll
    for (int e=0;e<16;++e){ const float sv = wred[j*16+e]; n2 = fmaf(sv,sv,n2); }
    vsh[tid] = wred[tid] * (n2/(1.f+n2)) * rsqrtf(n2 + 1e-9f);
  }
  __syncthreads();
  float vv[32];
  #pragma unroll
  for (int i=0;i<32;++i) vv[i] = vsh[i];

  #pragma unroll
  for (int i=0;i<32;++i) acc[i]=0.f;
  for (int n = tid; n < N_; n += NT){
    const float4 xa = *(const float4*)(x + ((size_t)b*N_ + n)*D_);
    const float4 xb = *(const float4*)(x + ((size_t)b*N_ + n)*D_ + 4);
    float u[32];
    #pragma unroll
    for (int j=0;j<J_;++j){
      const float* wp = W + ((size_t)j*N_ + n)*(E_*D_);
      #pragma unroll
      for (int e=0;e<E_;++e){
        const float4 wa = *(const float4*)(wp + e*8);
        const float4 wb = *(const float4*)(wp + e*8 + 4);
        float a;
        a = wa.x*xa.x; a = fmaf(wa.y,xa.y,a); a = fmaf(wa.z,xa.z,a); a = fmaf(wa.w,xa.w,a);
        a = fmaf(wb.x,xb.x,a); a = fmaf(wb.y,xb.y,a); a = fmaf(wb.z,xb.z,a); a = fmaf(wb.w,xb.w,a);
        u[j*16+e] = a;
      }
    }
    float l0=0.f, l1=0.f;
    #pragma unroll
    for (int e=0;e<16;++e){ l0 = fmaf(vv[e],u[e],l0); l1 = fmaf(vv[16+e],u[16+e],l1); }
    const float c0 = 1.f/(1.f + __expf(l1 - l0));
    const float c1 = 1.f - c0;
    #pragma unroll
    for (int e=0;e<16;++e){ acc[e] = fmaf(c0,u[e],acc[e]); acc[16+e] = fmaf(c1,u[16+e],acc[16+e]); }
  }
  #pragma unroll
  for (int i=0;i<32;++i){
    float v = acc[i];
    #pragma unroll
    for (int off=32; off; off>>=1) v += __shfl_xor(v, off);
    acc[i] = v;
  }
  __syncthreads();
  if (lane == 0){
    #pragma unroll
    for (int i=0;i<32;++i) wred[wv*33 + i] = acc[i];
  }
  __syncthreads();
  if (tid < 32){
    float s = 0.f;
    #pragma unroll
    for (int w=0;w<8;++w) s += wred[w*33 + tid];
    wred[tid] = s;
  }
  __syncthreads();
  if (tid < 32){
    const int j = tid >> 4; float n2 = 0.f;
    #pragma unroll
    for (int e=0;e<16;++e){ const float sv = wred[j*16+e]; n2 = fmaf(sv,sv,n2); }
    out[(size_t)b*32 + tid] = wred[tid] * (n2/(1.f+n2)) * rsqrtf(n2 + 1e-9f);
  }
}

extern "C" void kernel_launch(void* const* d_in, const int* in_sizes, int n_in,
                              void* d_out, int out_size, void* d_ws, size_t ws_size,
                              hipStream_t stream)
{
  const float* x = (const float*)d_in[0];   // [256,6912,8]
  const float* W = (const float*)d_in[1];   // [2,6912,16,8]
  if (n_in >= 2 && in_sizes[0] < in_sizes[1]){
    x = (const float*)d_in[1]; W = (const float*)d_in[0];
  }
  float* out = (float*)d_out;               // fp32 [256,2,16]

  const size_t need_main = (size_t)(8192 + 768*2048) * sizeof(float);  // ~6.1 MB

  if (ws_size >= need_main){
    float* wsf     = (float*)d_ws;
    float* v1      = wsf;           // 8192 floats
    float* partial = wsf + 8192;    // 768*2048 floats
    kpass1<<<dim3(CGX,4), 256, 0, stream>>>(x, W, partial);
    kred<true ><<<32, 256, 0, stream>>>(partial, v1);
    kpass2<<<dim3(CGX,4), 256, 0, stream>>>(x, W, v1, partial);
    kred<false><<<32, 256, 0, stream>>>(partial, out);
  } else if (ws_size >= 3*8192*sizeof(float)){
    float* wsf = (float*)d_ws;
    float* s1 = wsf;
    float* v1 = wsf + 8192;
    float* s2 = wsf + 16384;
    kzero<<<32, 256, 0, stream>>>(wsf);
    kpass1a<<<dim3(CGX,4), 256, 0, stream>>>(x, W, s1);
    ksquash_mid<<<2, 256, 0, stream>>>(s1, v1);
    kpass2a<<<dim3(CGX,4), 256, 0, stream>>>(x, W, v1, s2);
    ksquash_out<<<2, 256, 0, stream>>>(s2, out);
  } else {
    kmono<<<B_, NT, 0, stream>>>(x, W, out);
  }
}